// Round 15
// baseline (665.801 us; speedup 1.0000x reference)
//
#include <hip/hip_runtime.h>

typedef short bf16x8 __attribute__((ext_vector_type(8)));
typedef float f32x4 __attribute__((ext_vector_type(4)));

struct Ptr5 { const float* p[5]; };
struct UPtr5 { unsigned char* p[5]; };
struct FPtr5 { float* p[5]; };

__device__ __forceinline__ unsigned short f2bf(float f) {
  unsigned u = __float_as_uint(f);
  u += 0x7fffu + ((u >> 16) & 1u);
  return (unsigned short)(u >> 16);
}

__device__ __forceinline__ float bf2f(unsigned short h) {
  return __uint_as_float(((unsigned)h) << 16);
}

__device__ __forceinline__ void gload16(const void* g, void* l) {
  __builtin_amdgcn_global_load_lds((const __attribute__((address_space(1))) void*)g,
                                   (__attribute__((address_space(3))) void*)l, 16, 0, 0);
}

// 256B-row swizzled fragment read (128 bf16 per row)
__device__ __forceinline__ bf16x8 rf256(const unsigned char* lds, int row, int pb) {
  return *(const bf16x8*)(lds + row * 256 + (pb ^ ((row & 7) << 4)));
}

// ---------------- CSR build ----------------
__global__ void k_hist(const int* __restrict__ dst, int* __restrict__ deg, int E) {
  int e = blockIdx.x * blockDim.x + threadIdx.x;
  if (e < E) atomicAdd(&deg[dst[e]], 1);
}

__global__ __launch_bounds__(256) void k_scan_part(const int* __restrict__ deg,
                                                    int* __restrict__ bsum, int n) {
  int b = blockIdx.x, t = threadIdx.x;
  int base = b * 1024 + t * 4;
  int s = 0;
#pragma unroll
  for (int i = 0; i < 4; i++) {
    int idx = base + i;
    if (idx < n) s += deg[idx];
  }
  for (int off = 1; off < 64; off <<= 1) s += __shfl_xor(s, off);
  __shared__ int ws[4];
  if ((t & 63) == 0) ws[t >> 6] = s;
  __syncthreads();
  if (t == 0) bsum[b] = ws[0] + ws[1] + ws[2] + ws[3];
}

__global__ void k_scan_bsum(const int* __restrict__ bsum, int* __restrict__ boff,
                            int* __restrict__ row_start, int nb, int n) {
  int t = threadIdx.x;
  int orig = (t < nb) ? bsum[t] : 0;
  int v = orig;
  for (int off = 1; off < 64; off <<= 1) {
    int u = __shfl_up(v, off);
    if (t >= off) v += u;
  }
  if (t < nb) boff[t] = v - orig;
  if (t == nb - 1) row_start[n] = v;
}

__global__ __launch_bounds__(256) void k_scan_final(const int* __restrict__ deg,
                                                     const int* __restrict__ boff,
                                                     int* __restrict__ row_start,
                                                     int* __restrict__ cursor, int n) {
  int b = blockIdx.x, t = threadIdx.x;
  int lane = t & 63, wid = t >> 6;
  int base = b * 1024 + t * 4;
  int v[4];
  int s = 0;
#pragma unroll
  for (int i = 0; i < 4; i++) {
    int idx = base + i;
    v[i] = (idx < n) ? deg[idx] : 0;
    s += v[i];
  }
  int sc = s;
  for (int off = 1; off < 64; off <<= 1) {
    int u = __shfl_up(sc, off);
    if (lane >= off) sc += u;
  }
  __shared__ int ws[4];
  if (lane == 63) ws[wid] = sc;
  __syncthreads();
  int wbase = 0;
  for (int i = 0; i < wid; i++) wbase += ws[i];
  int run = boff[b] + wbase + sc - s;
#pragma unroll
  for (int i = 0; i < 4; i++) {
    int idx = base + i;
    if (idx < n) {
      row_start[idx] = run;
      cursor[idx] = run;
      run += v[i];
    }
  }
}

__global__ void k_scatter(const int* __restrict__ src, const int* __restrict__ dst,
                          int* __restrict__ cursor, int* __restrict__ edge_src, int E) {
  int e = blockIdx.x * blockDim.x + threadIdx.x;
  if (e < E) {
    int pos = atomicAdd(&cursor[dst[e]], 1);
    edge_src[pos] = src[e];
  }
}

// ---------------- cast x -> X.h (row stride 640) ----------------
__global__ void k_cast(const float* __restrict__ x, unsigned short* __restrict__ X, int n) {
  int i = blockIdx.x * blockDim.x + threadIdx.x;
  if (i >= n * 32) return;
  int r = i >> 5, c = (i & 31) * 4;
  float4 v = *(const float4*)(x + (size_t)r * 128 + c);
  ushort4 o;
  o.x = f2bf(v.x); o.y = f2bf(v.y); o.z = f2bf(v.z); o.w = f2bf(v.w);
  *(ushort4*)(X + (size_t)r * 640 + c) = o;
}

// ---------------- fold, all 5 layers (blockIdx.y = layer) ----------------
__global__ __launch_bounds__(256) void k_fold5(Ptr5 post_w, Ptr5 pre_w, Ptr5 pre_b,
                                                Ptr5 post_b, float* __restrict__ Whg_base,
                                                FPtr5 biasg) {
  int L = blockIdx.y;
  int id = blockIdx.x * blockDim.x + threadIdx.x;
  if (id >= 3 * 128 * 128) return;
  int g = id >> 14;
  int rem = id & 16383;
  int j = rem >> 7, k = rem & 127;
  const float* pw = post_w.p[L] + j * 1664 + g * 512 + 128;
  const float* prw = pre_w.p[L];
  float acc = 0.f, bacc = 0.f;
  for (int f = 0; f < 128; f++) {
    float wc = pw[f] + pw[128 + f] + pw[256 + f];
    acc += wc * prw[f * 256 + k];
    if (k == 0) bacc += wc * pre_b.p[L][f];
  }
  Whg_base[L * 49152 + id] = acc;
  if (k == 0) biasg.p[L][g * 128 + j] = bacc + ((g == 0) ? post_b.p[L][j] : 0.f);
}

// ---- repack post into FRAGMENT-ORDERED image: ((kt*4+wc)*6+f)*512 elems; elem = l16*32+lhi*8+e ----
__global__ void k_repack_post5(Ptr5 post_w, const float* __restrict__ Whg_base, UPtr5 img) {
  int L = blockIdx.y;
  int i = blockIdx.x * blockDim.x + threadIdx.x;
  if (i >= 384 * 640) return;
  int chunk = i >> 9;         // (kt*4+wc)*6+f
  int rem = i & 511;          // l16*32 + lhi*8 + e
  int f = chunk % 6;
  int wcc = (chunk / 6) & 3;
  int kt = chunk / 24;
  int l16 = rem >> 5;
  int lhi = (rem >> 3) & 3;
  int e = rem & 7;
  int row = (f >> 1) * 128 + wcc * 32 + (f & 1) * 16 + l16;
  int k = kt * 32 + lhi * 8 + e;
  int g = row >> 7, jj = row & 127;
  const float* Whg = Whg_base + L * 49152;
  float v;
  if (k < 128) v = ((g == 0) ? post_w.p[L][jj * 1664 + k] : 0.0f) + Whg[(g * 128 + jj) * 128 + k];
  else v = post_w.p[L][jj * 1664 + g * 512 + 128 + (k - 128)];
  ((unsigned short*)img.p[L])[i] = f2bf(v);
}

// ---------------- repack q (z=0) / lin (z=1), all 5 layers ----------------
__global__ void k_repack_ql5(Ptr5 pre_w, Ptr5 lin_w, UPtr5 qimg, UPtr5 limg) {
  int L = blockIdx.y;
  int which = blockIdx.z;
  int i = blockIdx.x * blockDim.x + threadIdx.x;
  if (i >= 128 * 128) return;
  int j = i >> 7, k = i & 127;
  float v = which ? lin_w.p[L][i] : pre_w.p[L][j * 256 + 128 + k];
  unsigned char* im = which ? limg.p[L] : qimg.p[L];
  int ch = k >> 3, e = k & 7;
  int off = j * 256 + ((ch * 16) ^ ((j & 7) << 4)) + e * 2;
  *(unsigned short*)(im + off) = f2bf(v);
}

// ---------------- GEMM1 (layer 0 only): Qb = X.h @ Wq^T ----------------
__global__ __launch_bounds__(512, 2) void k_gemm1(const unsigned short* __restrict__ X,
                                                   const unsigned char* __restrict__ Qimg,
                                                   unsigned short* __restrict__ Qb) {
  __shared__ __align__(16) unsigned char lds[65536];
  int tid = threadIdx.x;
  int w = tid >> 6, lane = tid & 63;
  int wr = w >> 2, wc = w & 3;
  int l16 = lane & 15, lhi = lane >> 4;
  int row0 = blockIdx.x * 128;
  const char* Xb = (const char*)X;
#pragma unroll
  for (int j = 0; j < 4; j++) {
    int off = w * 4096 + j * 1024 + lane * 16;
    int r = off >> 8, pos = off & 255;
    int ch = (pos ^ ((r & 7) << 4)) >> 4;
    gload16(Xb + (size_t)(row0 + r) * 1280 + ch * 16, lds + w * 4096 + j * 1024);
  }
#pragma unroll
  for (int j = 0; j < 4; j++) {
    int off = w * 4096 + j * 1024;
    gload16(Qimg + off + lane * 16, lds + 32768 + off);
  }
  __syncthreads();
  f32x4 acc[4][2];
#pragma unroll
  for (int m = 0; m < 4; m++)
#pragma unroll
    for (int j = 0; j < 2; j++) acc[m][j] = (f32x4){0.f, 0.f, 0.f, 0.f};
#pragma unroll
  for (int ks = 0; ks < 4; ks++) {
    int pb = ks * 64 + lhi * 16;
    bf16x8 af[4], bfr[2];
#pragma unroll
    for (int m = 0; m < 4; m++) af[m] = rf256(lds, wr * 64 + m * 16 + l16, pb);
#pragma unroll
    for (int j = 0; j < 2; j++) bfr[j] = rf256(lds + 32768, wc * 32 + j * 16 + l16, pb);
#pragma unroll
    for (int m = 0; m < 4; m++)
#pragma unroll
      for (int j = 0; j < 2; j++)
        acc[m][j] = __builtin_amdgcn_mfma_f32_16x16x32_bf16(af[m], bfr[j], acc[m][j], 0, 0, 0);
  }
#pragma unroll
  for (int m = 0; m < 4; m++)
#pragma unroll
    for (int j = 0; j < 2; j++)
#pragma unroll
      for (int i = 0; i < 4; i++) {
        int r = row0 + wr * 64 + m * 16 + lhi * 4 + i;
        int c = wc * 32 + j * 16 + l16;
        Qb[(size_t)r * 128 + c] = f2bf(acc[m][j][i]);
      }
}

// ---------------- aggregation: 2 independent nodes per wave (half-wave per node) ----------------
__global__ __launch_bounds__(256) void k_agg(const unsigned short* __restrict__ Qb,
                                              const int* __restrict__ row_start,
                                              const int* __restrict__ edge_src,
                                              const unsigned short* __restrict__ X_h,
                                              const float* __restrict__ pre_w,
                                              const float* __restrict__ pre_b,
                                              const float* __restrict__ adl,
                                              unsigned short* __restrict__ X,
                                              float* __restrict__ scale,
                                              float* __restrict__ inv_scale, int n) {
  int wv = (blockIdx.x * blockDim.x + threadIdx.x) >> 6;
  int lane = threadIdx.x & 63;
  int half = lane >> 5, fl = lane & 31;
  int v = 2 * wv + half;
  if (v >= n) return;
  int r0 = row_start[v], r1 = row_start[v + 1];
  int dg = r1 - r0;
  float mean[4], mnv[4], mxv[4], sdv[4];
  if (dg > 0) {
    float s[4] = {0.f, 0.f, 0.f, 0.f}, q[4] = {0.f, 0.f, 0.f, 0.f};
    float mn[4], mx[4];
#pragma unroll
    for (int t = 0; t < 4; t++) { mn[t] = INFINITY; mx[t] = -INFINITY; }
    const unsigned char* qbase = (const unsigned char*)Qb;
#define ACC4(U)                                                              \
  do {                                                                       \
    float f0 = __uint_as_float((U).x << 16);                                 \
    float f1 = __uint_as_float((U).x & 0xffff0000u);                         \
    float f2 = __uint_as_float((U).y << 16);                                 \
    float f3 = __uint_as_float((U).y & 0xffff0000u);                         \
    s[0] += f0; s[1] += f1; s[2] += f2; s[3] += f3;                          \
    q[0] += f0 * f0; q[1] += f1 * f1; q[2] += f2 * f2; q[3] += f3 * f3;      \
    mn[0] = fminf(mn[0], f0); mn[1] = fminf(mn[1], f1);                      \
    mn[2] = fminf(mn[2], f2); mn[3] = fminf(mn[3], f3);                      \
    mx[0] = fmaxf(mx[0], f0); mx[1] = fmaxf(mx[1], f1);                      \
    mx[2] = fmaxf(mx[2], f2); mx[3] = fmaxf(mx[3], f3);                      \
  } while (0)
    int e = r0;
    for (; e + 3 < r1; e += 4) {
      int sa = edge_src[e], sb = edge_src[e + 1], sc = edge_src[e + 2], sd = edge_src[e + 3];
      uint2 ua = *(const uint2*)(qbase + (size_t)sa * 256 + 8 * fl);
      uint2 ub = *(const uint2*)(qbase + (size_t)sb * 256 + 8 * fl);
      uint2 uc = *(const uint2*)(qbase + (size_t)sc * 256 + 8 * fl);
      uint2 ud = *(const uint2*)(qbase + (size_t)sd * 256 + 8 * fl);
      ACC4(ua); ACC4(ub); ACC4(uc); ACC4(ud);
    }
    for (; e < r1; e++) {
      int sa = edge_src[e];
      uint2 ua = *(const uint2*)(qbase + (size_t)sa * 256 + 8 * fl);
      ACC4(ua);
    }
#undef ACC4
    float invd = 1.0f / (float)dg;
#pragma unroll
    for (int t = 0; t < 4; t++) {
      mean[t] = s[t] * invd;
      float var = fmaxf(q[t] * invd - mean[t] * mean[t], 0.f);
      sdv[t] = sqrtf(var + 1e-5f);
      mnv[t] = mn[t]; mxv[t] = mx[t];
    }
  } else {
    const unsigned short* hv = X_h + (size_t)v * 640;
#pragma unroll
    for (int t = 0; t < 4; t++) {
      int j = 4 * fl + t;
      float c = pre_b[j];
      for (int k = 0; k < 128; k++) c += bf2f(hv[k]) * pre_w[j * 256 + k];
      mean[t] = mnv[t] = mxv[t] = -c;
      sdv[t] = sqrtf(1e-5f);
    }
  }
  unsigned short* row = X + (size_t)v * 640 + 128;
  ushort4 wm, wn, wx, ws;
  wm.x = f2bf(mean[0]); wm.y = f2bf(mean[1]); wm.z = f2bf(mean[2]); wm.w = f2bf(mean[3]);
  wn.x = f2bf(mnv[0]);  wn.y = f2bf(mnv[1]);  wn.z = f2bf(mnv[2]);  wn.w = f2bf(mnv[3]);
  wx.x = f2bf(mxv[0]);  wx.y = f2bf(mxv[1]);  wx.z = f2bf(mxv[2]);  wx.w = f2bf(mxv[3]);
  ws.x = f2bf(sdv[0]);  ws.y = f2bf(sdv[1]);  ws.z = f2bf(sdv[2]);  ws.w = f2bf(sdv[3]);
  *(ushort4*)(row + 4 * fl) = wm;
  *(ushort4*)(row + 128 + 4 * fl) = wn;
  *(ushort4*)(row + 256 + 4 * fl) = wx;
  *(ushort4*)(row + 384 + 4 * fl) = ws;
  if (fl == 0) {
    float degf = (float)dg;
    float sc = logf(fmaxf(degf, 1.0f) + 1.0f) / adl[0];
    scale[v] = sc;
    inv_scale[v] = 1.0f / sc;
  }
}

// ------- fused: post GEMM (K=640, register-direct flatmm, no LDS/no barriers) + combine + lin + next-Q -------
// 64KB LDS (phases B/C only) -> 2 blocks/CU
__global__ __launch_bounds__(512, 2) void k_fused(const unsigned short* __restrict__ X,
                                                   const unsigned char* __restrict__ Bimg,
                                                   const unsigned char* __restrict__ Limg,
                                                   const unsigned char* __restrict__ Qimg,
                                                   const float* __restrict__ scale,
                                                   const float* __restrict__ invs,
                                                   const float* __restrict__ biasg,
                                                   const float* __restrict__ lin_b,
                                                   unsigned short* __restrict__ Xh,
                                                   unsigned short* __restrict__ Qb,
                                                   float* __restrict__ Fout,
                                                   int M, int write_f32, int doC) {
  // phase B: lin @0 (32KB), y @32768 (32KB, 256B rows); phase C: Wq @0, h @32768
  __shared__ __align__(16) unsigned char lds[65536];
  int tid = threadIdx.x;
  int w = tid >> 6, lane = tid & 63;
  int wr = w >> 2, wc = w & 3;
  int l16 = lane & 15, lhi = lane >> 4;
  int row0 = blockIdx.x * 128;
  const unsigned char* Xb = (const unsigned char*)X;

  // per-lane base pointers
  const unsigned char* Ab[4];
#pragma unroll
  for (int m = 0; m < 4; m++)
    Ab[m] = Xb + (size_t)(row0 + wr * 64 + m * 16 + l16) * 1280 + lhi * 16;
  const unsigned char* Bb = Bimg + wc * 6144 + l16 * 64 + lhi * 16;

  f32x4 acc[4][6];
#pragma unroll
  for (int m = 0; m < 4; m++)
#pragma unroll
    for (int f = 0; f < 6; f++) acc[m][f] = (f32x4){0.f, 0.f, 0.f, 0.f};

  // phase A: 20 K-tiles, pure register pipeline (compiler-scheduled)
#pragma unroll
  for (int kt = 0; kt < 20; kt++) {
    bf16x8 af[4], bfr[6];
#pragma unroll
    for (int m = 0; m < 4; m++) af[m] = *(const bf16x8*)(Ab[m] + kt * 64);
#pragma unroll
    for (int f = 0; f < 6; f++) bfr[f] = *(const bf16x8*)(Bb + kt * 24576 + f * 1024);
#pragma unroll
    for (int m = 0; m < 4; m++)
#pragma unroll
      for (int f = 0; f < 6; f++)
        acc[m][f] = __builtin_amdgcn_mfma_f32_16x16x32_bf16(af[m], bfr[f], acc[m][f], 0, 0, 0);
  }

  // stage lin image into @0; combine epilogue hides the load
#pragma unroll
  for (int j = 0; j < 4; j++) {
    int off = w * 4096 + j * 1024;
    gload16(Limg + off + lane * 16, lds + off);
  }
  // combine epilogue -> y into LDS @32768 (256B swizzled rows)
#pragma unroll
  for (int m = 0; m < 4; m++)
#pragma unroll
    for (int i = 0; i < 4; i++) {
      int rl = wr * 64 + m * 16 + lhi * 4 + i;
      int r = row0 + rl;
      float s = scale[r], iv = invs[r];
      int swz = (rl & 7) << 4;
#pragma unroll
      for (int j = 0; j < 2; j++) {
        int c = wc * 32 + j * 16 + l16;
        float v = acc[m][j][i] + s * acc[m][2 + j][i] + iv * acc[m][4 + j][i] + biasg[c] +
                  s * biasg[128 + c] + iv * biasg[256 + c];
        *(unsigned short*)(lds + 32768 + rl * 256 + ((2 * c) ^ swz)) = f2bf(v);
      }
    }
  __syncthreads();  // drains lin stage + makes y visible

  // phase B: h = relu(y @ lin^T + lin_b)
  f32x4 acc2[4][2];
#pragma unroll
  for (int m = 0; m < 4; m++)
#pragma unroll
    for (int j = 0; j < 2; j++) acc2[m][j] = (f32x4){0.f, 0.f, 0.f, 0.f};
#pragma unroll
  for (int ks = 0; ks < 4; ks++) {
    int pb = ks * 64 + lhi * 16;
    bf16x8 af[4], bfr[2];
#pragma unroll
    for (int m = 0; m < 4; m++) af[m] = rf256(lds + 32768, wr * 64 + m * 16 + l16, pb);
#pragma unroll
    for (int j = 0; j < 2; j++) bfr[j] = rf256(lds, wc * 32 + j * 16 + l16, pb);
#pragma unroll
    for (int m = 0; m < 4; m++)
#pragma unroll
      for (int j = 0; j < 2; j++)
        acc2[m][j] = __builtin_amdgcn_mfma_f32_16x16x32_bf16(af[m], bfr[j], acc2[m][j], 0, 0, 0);
  }
  __syncthreads();  // all y/lin reads complete before overwrite

  // stage Wq @0; h epilogue: write Xh global (+Fout) and h into LDS @32768
  if (doC) {
#pragma unroll
    for (int j = 0; j < 4; j++) {
      int off = w * 4096 + j * 1024;
      gload16(Qimg + off + lane * 16, lds + off);
    }
  }
#pragma unroll
  for (int m = 0; m < 4; m++)
#pragma unroll
    for (int j = 0; j < 2; j++)
#pragma unroll
      for (int i = 0; i < 4; i++) {
        int rl = wr * 64 + m * 16 + lhi * 4 + i;
        int r = row0 + rl;
        int c = wc * 32 + j * 16 + l16;
        float v = fmaxf(acc2[m][j][i] + lin_b[c], 0.0f);
        unsigned short hb = f2bf(v);
        Xh[(size_t)r * 640 + c] = hb;
        if (doC) *(unsigned short*)(lds + 32768 + rl * 256 + ((2 * c) ^ ((rl & 7) << 4))) = hb;
        if (write_f32 && r < M) Fout[(size_t)r * 128 + c] = v;
      }
  if (!doC) return;
  __syncthreads();  // h visible + Wq staged (vmcnt drained)

  // phase C: Qb_next = h @ Wq^T
  f32x4 acc3[4][2];
#pragma unroll
  for (int m = 0; m < 4; m++)
#pragma unroll
    for (int j = 0; j < 2; j++) acc3[m][j] = (f32x4){0.f, 0.f, 0.f, 0.f};
#pragma unroll
  for (int ks = 0; ks < 4; ks++) {
    int pb = ks * 64 + lhi * 16;
    bf16x8 af[4], bfr[2];
#pragma unroll
    for (int m = 0; m < 4; m++) af[m] = rf256(lds + 32768, wr * 64 + m * 16 + l16, pb);
#pragma unroll
    for (int j = 0; j < 2; j++) bfr[j] = rf256(lds, wc * 32 + j * 16 + l16, pb);
#pragma unroll
    for (int m = 0; m < 4; m++)
#pragma unroll
      for (int j = 0; j < 2; j++)
        acc3[m][j] = __builtin_amdgcn_mfma_f32_16x16x32_bf16(af[m], bfr[j], acc3[m][j], 0, 0, 0);
  }
#pragma unroll
  for (int m = 0; m < 4; m++)
#pragma unroll
    for (int j = 0; j < 2; j++)
#pragma unroll
      for (int i = 0; i < 4; i++) {
        int r = row0 + wr * 64 + m * 16 + lhi * 4 + i;
        int c = wc * 32 + j * 16 + l16;
        Qb[(size_t)r * 128 + c] = f2bf(acc3[m][j][i]);
      }
}

// ---------------- host ----------------
extern "C" void kernel_launch(void* const* d_in, const int* in_sizes, int n_in,
                              void* d_out, int out_size, void* d_ws, size_t ws_size,
                              hipStream_t stream) {
  const float* x = (const float*)d_in[0];
  const int* eidx = (const int*)d_in[1];
  int n = in_sizes[0] / 128;
  int E = in_sizes[1] / 2;
  int n_pad = (n + 127) & ~127;
  const int* src = eidx;
  const int* dst = eidx + E;

  Ptr5 pre_w, pre_b, adl, post_w, post_b, lin_w, lin_b;
  for (int i = 0; i < 5; i++) {
    pre_w.p[i] = (const float*)d_in[2 + i * 7 + 0];
    pre_b.p[i] = (const float*)d_in[2 + i * 7 + 1];
    adl.p[i] = (const float*)d_in[2 + i * 7 + 2];
    post_w.p[i] = (const float*)d_in[2 + i * 7 + 3];
    post_b.p[i] = (const float*)d_in[2 + i * 7 + 4];
    lin_w.p[i] = (const float*)d_in[2 + i * 7 + 5];
    lin_b.p[i] = (const float*)d_in[2 + i * 7 + 6];
  }

  char* ws = (char*)d_ws;
  size_t off = 0;
  auto alloc = [&](size_t bytes) {
    char* p = ws + off;
    off += (bytes + 255) & ~(size_t)255;
    return p;
  };
  unsigned short* X = (unsigned short*)alloc((size_t)n_pad * 640 * 2);  // [h | agg]
  unsigned short* Qb = (unsigned short*)alloc((size_t)n_pad * 128 * 2);
  float* scale = (float*)alloc((size_t)n_pad * 4);
  float* invs = (float*)alloc((size_t)n_pad * 4);
  int* deg = (int*)alloc((size_t)n * 4);
  int* row_start = (int*)alloc((size_t)(n + 1) * 4);
  int* cursor = (int*)alloc((size_t)n * 4);
  int* edge_src = (int*)alloc((size_t)E * 4);
  int nb = (n + 1023) / 1024;
  int* bsum = (int*)alloc((size_t)nb * 4);
  int* boff = (int*)alloc((size_t)nb * 4);
  float* Whg_base = (float*)alloc((size_t)5 * 3 * 128 * 128 * 4);
  UPtr5 Bpost, Lin, Qimg;
  FPtr5 biasg;
  for (int i = 0; i < 5; i++) {
    Bpost.p[i] = (unsigned char*)alloc(491520);
    Lin.p[i] = (unsigned char*)alloc(32768);
    Qimg.p[i] = (unsigned char*)alloc(32768);
    biasg.p[i] = (float*)alloc(384 * 4);
  }

  hipMemsetAsync(deg, 0, (size_t)n * 4, stream);
  k_hist<<<(E + 255) / 256, 256, 0, stream>>>(dst, deg, E);
  k_scan_part<<<nb, 256, 0, stream>>>(deg, bsum, n);
  k_scan_bsum<<<1, 64, 0, stream>>>(bsum, boff, row_start, nb, n);
  k_scan_final<<<nb, 256, 0, stream>>>(deg, boff, row_start, cursor, n);
  k_scatter<<<(E + 255) / 256, 256, 0, stream>>>(src, dst, cursor, edge_src, E);
  k_cast<<<(n * 32 + 255) / 256, 256, 0, stream>>>(x, X, n);
  k_fold5<<<dim3(192, 5), 256, 0, stream>>>(post_w, pre_w, pre_b, post_b, Whg_base, biasg);
  k_repack_post5<<<dim3(960, 5), 256, 0, stream>>>(post_w, Whg_base, Bpost);
  k_repack_ql5<<<dim3(64, 5, 2), 256, 0, stream>>>(pre_w, lin_w, Qimg, Lin);

  int gblocks = n_pad / 128;
  k_gemm1<<<gblocks, 512, 0, stream>>>(X, Qimg.p[0], Qb);
  for (int L = 0; L < 5; L++) {
    k_agg<<<(n + 7) / 8, 256, 0, stream>>>(Qb, row_start, edge_src, X, pre_w.p[L], pre_b.p[L],
                                           adl.p[L], X, scale, invs, n);
    k_fused<<<gblocks, 512, 0, stream>>>(X, Bpost.p[L], Lin.p[L],
                                         (L < 4) ? Qimg.p[L + 1] : Qimg.p[0], scale, invs,
                                         biasg.p[L], lin_b.p[L], X, Qb, (float*)d_out, n,
                                         (L == 4) ? 1 : 0, (L < 4) ? 1 : 0);
  }
}

// Round 17
// 501.580 us; speedup vs baseline: 1.3274x; 1.3274x over previous
//
#include <hip/hip_runtime.h>

typedef short bf16x8 __attribute__((ext_vector_type(8)));
typedef float f32x4 __attribute__((ext_vector_type(4)));

struct Ptr5 { const float* p[5]; };
struct UPtr5 { unsigned char* p[5]; };
struct FPtr5 { float* p[5]; };

__device__ __forceinline__ unsigned short f2bf(float f) {
  unsigned u = __float_as_uint(f);
  u += 0x7fffu + ((u >> 16) & 1u);
  return (unsigned short)(u >> 16);
}

__device__ __forceinline__ float bf2f(unsigned short h) {
  return __uint_as_float(((unsigned)h) << 16);
}

__device__ __forceinline__ void gload16(const void* g, void* l) {
  __builtin_amdgcn_global_load_lds((const __attribute__((address_space(1))) void*)g,
                                   (__attribute__((address_space(3))) void*)l, 16, 0, 0);
}

// 64B-row swizzled fragment read: chunk ^= (row>>1)&3 -> 2-way max (free)
__device__ __forceinline__ bf16x8 rf64(const unsigned char* lds, int row, int pb) {
  return *(const bf16x8*)(lds + row * 64 + (pb ^ ((((row) >> 1) & 3) << 4)));
}
// 256B-row swizzled fragment read (128 bf16 per row)
__device__ __forceinline__ bf16x8 rf256(const unsigned char* lds, int row, int pb) {
  return *(const bf16x8*)(lds + row * 256 + (pb ^ ((row & 7) << 4)));
}

// ---------------- CSR build ----------------
__global__ void k_hist(const int* __restrict__ dst, int* __restrict__ deg, int E) {
  int e = blockIdx.x * blockDim.x + threadIdx.x;
  if (e < E) atomicAdd(&deg[dst[e]], 1);
}

__global__ __launch_bounds__(256) void k_scan_part(const int* __restrict__ deg,
                                                    int* __restrict__ bsum, int n) {
  int b = blockIdx.x, t = threadIdx.x;
  int base = b * 1024 + t * 4;
  int s = 0;
#pragma unroll
  for (int i = 0; i < 4; i++) {
    int idx = base + i;
    if (idx < n) s += deg[idx];
  }
  for (int off = 1; off < 64; off <<= 1) s += __shfl_xor(s, off);
  __shared__ int ws[4];
  if ((t & 63) == 0) ws[t >> 6] = s;
  __syncthreads();
  if (t == 0) bsum[b] = ws[0] + ws[1] + ws[2] + ws[3];
}

__global__ void k_scan_bsum(const int* __restrict__ bsum, int* __restrict__ boff,
                            int* __restrict__ row_start, int nb, int n) {
  int t = threadIdx.x;
  int orig = (t < nb) ? bsum[t] : 0;
  int v = orig;
  for (int off = 1; off < 64; off <<= 1) {
    int u = __shfl_up(v, off);
    if (t >= off) v += u;
  }
  if (t < nb) boff[t] = v - orig;
  if (t == nb - 1) row_start[n] = v;
}

__global__ __launch_bounds__(256) void k_scan_final(const int* __restrict__ deg,
                                                     const int* __restrict__ boff,
                                                     int* __restrict__ row_start,
                                                     int* __restrict__ cursor, int n) {
  int b = blockIdx.x, t = threadIdx.x;
  int lane = t & 63, wid = t >> 6;
  int base = b * 1024 + t * 4;
  int v[4];
  int s = 0;
#pragma unroll
  for (int i = 0; i < 4; i++) {
    int idx = base + i;
    v[i] = (idx < n) ? deg[idx] : 0;
    s += v[i];
  }
  int sc = s;
  for (int off = 1; off < 64; off <<= 1) {
    int u = __shfl_up(sc, off);
    if (lane >= off) sc += u;
  }
  __shared__ int ws[4];
  if (lane == 63) ws[wid] = sc;
  __syncthreads();
  int wbase = 0;
  for (int i = 0; i < wid; i++) wbase += ws[i];
  int run = boff[b] + wbase + sc - s;
#pragma unroll
  for (int i = 0; i < 4; i++) {
    int idx = base + i;
    if (idx < n) {
      row_start[idx] = run;
      cursor[idx] = run;
      run += v[i];
    }
  }
}

__global__ void k_scatter(const int* __restrict__ src, const int* __restrict__ dst,
                          int* __restrict__ cursor, int* __restrict__ edge_src, int E) {
  int e = blockIdx.x * blockDim.x + threadIdx.x;
  if (e < E) {
    int pos = atomicAdd(&cursor[dst[e]], 1);
    edge_src[pos] = src[e];
  }
}

// ---------------- cast x -> X.h (row stride 640) ----------------
__global__ void k_cast(const float* __restrict__ x, unsigned short* __restrict__ X, int n) {
  int i = blockIdx.x * blockDim.x + threadIdx.x;
  if (i >= n * 32) return;
  int r = i >> 5, c = (i & 31) * 4;
  float4 v = *(const float4*)(x + (size_t)r * 128 + c);
  ushort4 o;
  o.x = f2bf(v.x); o.y = f2bf(v.y); o.z = f2bf(v.z); o.w = f2bf(v.w);
  *(ushort4*)(X + (size_t)r * 640 + c) = o;
}

// ---------------- fold, all 5 layers (blockIdx.y = layer) ----------------
__global__ __launch_bounds__(256) void k_fold5(Ptr5 post_w, Ptr5 pre_w, Ptr5 pre_b,
                                                Ptr5 post_b, float* __restrict__ Whg_base,
                                                FPtr5 biasg) {
  int L = blockIdx.y;
  int id = blockIdx.x * blockDim.x + threadIdx.x;
  if (id >= 3 * 128 * 128) return;
  int g = id >> 14;
  int rem = id & 16383;
  int j = rem >> 7, k = rem & 127;
  const float* pw = post_w.p[L] + j * 1664 + g * 512 + 128;
  const float* prw = pre_w.p[L];
  float acc = 0.f, bacc = 0.f;
  for (int f = 0; f < 128; f++) {
    float wc = pw[f] + pw[128 + f] + pw[256 + f];
    acc += wc * prw[f * 256 + k];
    if (k == 0) bacc += wc * pre_b.p[L][f];
  }
  Whg_base[L * 49152 + id] = acc;
  if (k == 0) biasg.p[L][g * 128 + j] = bacc + ((g == 0) ? post_b.p[L][j] : 0.f);
}

// ---------------- repack post (20 K-tiles x 384 rows x 64B, chunk^=(r>>1)&3), all 5 layers ----------------
__global__ void k_repack_post5(Ptr5 post_w, const float* __restrict__ Whg_base, UPtr5 img) {
  int L = blockIdx.y;
  int i = blockIdx.x * blockDim.x + threadIdx.x;
  if (i >= 384 * 640) return;
  const float* pwL = post_w.p[L];
  const float* Whg = Whg_base + L * 49152;
  unsigned char* im = img.p[L];
  int r = i / 640, k = i - r * 640;
  int g = r >> 7, jj = r & 127;
  float v;
  if (k < 128) v = ((g == 0) ? pwL[jj * 1664 + k] : 0.0f) + Whg[(g * 128 + jj) * 128 + k];
  else v = pwL[jj * 1664 + g * 512 + 128 + (k - 128)];
  int kt = k >> 5, kl = k & 31;
  int ch = kl >> 3, e = kl & 7;
  int off = kt * 24576 + r * 64 + ((ch ^ ((r >> 1) & 3)) << 4) + e * 2;
  *(unsigned short*)(im + off) = f2bf(v);
}

// ---------------- repack q (z=0) / lin (z=1), all 5 layers ----------------
__global__ void k_repack_ql5(Ptr5 pre_w, Ptr5 lin_w, UPtr5 qimg, UPtr5 limg) {
  int L = blockIdx.y;
  int which = blockIdx.z;
  int i = blockIdx.x * blockDim.x + threadIdx.x;
  if (i >= 128 * 128) return;
  int j = i >> 7, k = i & 127;
  float v = which ? lin_w.p[L][i] : pre_w.p[L][j * 256 + 128 + k];
  unsigned char* im = which ? limg.p[L] : qimg.p[L];
  int ch = k >> 3, e = k & 7;
  int off = j * 256 + ((ch * 16) ^ ((j & 7) << 4)) + e * 2;
  *(unsigned short*)(im + off) = f2bf(v);
}

// ---------------- GEMM1 (layer 0 only): Qb = X.h @ Wq^T ----------------
__global__ __launch_bounds__(512, 2) void k_gemm1(const unsigned short* __restrict__ X,
                                                   const unsigned char* __restrict__ Qimg,
                                                   unsigned short* __restrict__ Qb) {
  __shared__ __align__(16) unsigned char lds[65536];
  int tid = threadIdx.x;
  int w = tid >> 6, lane = tid & 63;
  int wr = w >> 2, wc = w & 3;
  int l16 = lane & 15, lhi = lane >> 4;
  int row0 = blockIdx.x * 128;
  const char* Xb = (const char*)X;
#pragma unroll
  for (int j = 0; j < 4; j++) {
    int off = w * 4096 + j * 1024 + lane * 16;
    int r = off >> 8, pos = off & 255;
    int ch = (pos ^ ((r & 7) << 4)) >> 4;
    gload16(Xb + (size_t)(row0 + r) * 1280 + ch * 16, lds + w * 4096 + j * 1024);
  }
#pragma unroll
  for (int j = 0; j < 4; j++) {
    int off = w * 4096 + j * 1024;
    gload16(Qimg + off + lane * 16, lds + 32768 + off);
  }
  __syncthreads();
  f32x4 acc[4][2];
#pragma unroll
  for (int m = 0; m < 4; m++)
#pragma unroll
    for (int j = 0; j < 2; j++) acc[m][j] = (f32x4){0.f, 0.f, 0.f, 0.f};
#pragma unroll
  for (int ks = 0; ks < 4; ks++) {
    int pb = ks * 64 + lhi * 16;
    bf16x8 af[4], bfr[2];
#pragma unroll
    for (int m = 0; m < 4; m++) af[m] = rf256(lds, wr * 64 + m * 16 + l16, pb);
#pragma unroll
    for (int j = 0; j < 2; j++) bfr[j] = rf256(lds + 32768, wc * 32 + j * 16 + l16, pb);
#pragma unroll
    for (int m = 0; m < 4; m++)
#pragma unroll
      for (int j = 0; j < 2; j++)
        acc[m][j] = __builtin_amdgcn_mfma_f32_16x16x32_bf16(af[m], bfr[j], acc[m][j], 0, 0, 0);
  }
#pragma unroll
  for (int m = 0; m < 4; m++)
#pragma unroll
    for (int j = 0; j < 2; j++)
#pragma unroll
      for (int i = 0; i < 4; i++) {
        int r = row0 + wr * 64 + m * 16 + lhi * 4 + i;
        int c = wc * 32 + j * 16 + l16;
        Qb[(size_t)r * 128 + c] = f2bf(acc[m][j][i]);
      }
}

// ---------------- aggregation: 2 independent nodes per wave (half-wave per node) ----------------
__global__ __launch_bounds__(256) void k_agg(const unsigned short* __restrict__ Qb,
                                              const int* __restrict__ row_start,
                                              const int* __restrict__ edge_src,
                                              const unsigned short* __restrict__ X_h,
                                              const float* __restrict__ pre_w,
                                              const float* __restrict__ pre_b,
                                              const float* __restrict__ adl,
                                              unsigned short* __restrict__ X,
                                              float* __restrict__ scale,
                                              float* __restrict__ inv_scale, int n) {
  int wv = (blockIdx.x * blockDim.x + threadIdx.x) >> 6;
  int lane = threadIdx.x & 63;
  int half = lane >> 5, fl = lane & 31;
  int v = 2 * wv + half;
  if (v >= n) return;
  int r0 = row_start[v], r1 = row_start[v + 1];
  int dg = r1 - r0;
  float mean[4], mnv[4], mxv[4], sdv[4];
  if (dg > 0) {
    float s[4] = {0.f, 0.f, 0.f, 0.f}, q[4] = {0.f, 0.f, 0.f, 0.f};
    float mn[4], mx[4];
#pragma unroll
    for (int t = 0; t < 4; t++) { mn[t] = INFINITY; mx[t] = -INFINITY; }
    const unsigned char* qbase = (const unsigned char*)Qb;
#define ACC4(U)                                                              \
  do {                                                                       \
    float f0 = __uint_as_float((U).x << 16);                                 \
    float f1 = __uint_as_float((U).x & 0xffff0000u);                         \
    float f2 = __uint_as_float((U).y << 16);                                 \
    float f3 = __uint_as_float((U).y & 0xffff0000u);                         \
    s[0] += f0; s[1] += f1; s[2] += f2; s[3] += f3;                          \
    q[0] += f0 * f0; q[1] += f1 * f1; q[2] += f2 * f2; q[3] += f3 * f3;      \
    mn[0] = fminf(mn[0], f0); mn[1] = fminf(mn[1], f1);                      \
    mn[2] = fminf(mn[2], f2); mn[3] = fminf(mn[3], f3);                      \
    mx[0] = fmaxf(mx[0], f0); mx[1] = fmaxf(mx[1], f1);                      \
    mx[2] = fmaxf(mx[2], f2); mx[3] = fmaxf(mx[3], f3);                      \
  } while (0)
    int e = r0;
    for (; e + 3 < r1; e += 4) {
      int sa = edge_src[e], sb = edge_src[e + 1], sc = edge_src[e + 2], sd = edge_src[e + 3];
      uint2 ua = *(const uint2*)(qbase + (size_t)sa * 256 + 8 * fl);
      uint2 ub = *(const uint2*)(qbase + (size_t)sb * 256 + 8 * fl);
      uint2 uc = *(const uint2*)(qbase + (size_t)sc * 256 + 8 * fl);
      uint2 ud = *(const uint2*)(qbase + (size_t)sd * 256 + 8 * fl);
      ACC4(ua); ACC4(ub); ACC4(uc); ACC4(ud);
    }
    for (; e < r1; e++) {
      int sa = edge_src[e];
      uint2 ua = *(const uint2*)(qbase + (size_t)sa * 256 + 8 * fl);
      ACC4(ua);
    }
#undef ACC4
    float invd = 1.0f / (float)dg;
#pragma unroll
    for (int t = 0; t < 4; t++) {
      mean[t] = s[t] * invd;
      float var = fmaxf(q[t] * invd - mean[t] * mean[t], 0.f);
      sdv[t] = sqrtf(var + 1e-5f);
      mnv[t] = mn[t]; mxv[t] = mx[t];
    }
  } else {
    const unsigned short* hv = X_h + (size_t)v * 640;
#pragma unroll
    for (int t = 0; t < 4; t++) {
      int j = 4 * fl + t;
      float c = pre_b[j];
      for (int k = 0; k < 128; k++) c += bf2f(hv[k]) * pre_w[j * 256 + k];
      mean[t] = mnv[t] = mxv[t] = -c;
      sdv[t] = sqrtf(1e-5f);
    }
  }
  unsigned short* row = X + (size_t)v * 640 + 128;
  ushort4 wm, wn, wx, ws;
  wm.x = f2bf(mean[0]); wm.y = f2bf(mean[1]); wm.z = f2bf(mean[2]); wm.w = f2bf(mean[3]);
  wn.x = f2bf(mnv[0]);  wn.y = f2bf(mnv[1]);  wn.z = f2bf(mnv[2]);  wn.w = f2bf(mnv[3]);
  wx.x = f2bf(mxv[0]);  wx.y = f2bf(mxv[1]);  wx.z = f2bf(mxv[2]);  wx.w = f2bf(mxv[3]);
  ws.x = f2bf(sdv[0]);  ws.y = f2bf(sdv[1]);  ws.z = f2bf(sdv[2]);  ws.w = f2bf(sdv[3]);
  *(ushort4*)(row + 4 * fl) = wm;
  *(ushort4*)(row + 128 + 4 * fl) = wn;
  *(ushort4*)(row + 256 + 4 * fl) = wx;
  *(ushort4*)(row + 384 + 4 * fl) = ws;
  if (fl == 0) {
    float degf = (float)dg;
    float sc = logf(fmaxf(degf, 1.0f) + 1.0f) / adl[0];
    scale[v] = sc;
    inv_scale[v] = 1.0f / sc;
  }
}

// ------- fused: BM=64, 256 threads, BK=32 2-buf counted-vmcnt + combine + lin + relu + next-Q -------
// 56KB LDS -> 2 blocks/CU; 782 blocks (halved tail granularity)
__global__ __launch_bounds__(256, 2) void k_fused(const unsigned short* __restrict__ X,
                                                   const unsigned char* __restrict__ Bimg,
                                                   const unsigned char* __restrict__ Limg,
                                                   const unsigned char* __restrict__ Qimg,
                                                   const float* __restrict__ scale,
                                                   const float* __restrict__ invs,
                                                   const float* __restrict__ biasg,
                                                   const float* __restrict__ lin_b,
                                                   unsigned short* __restrict__ Xh,
                                                   unsigned short* __restrict__ Qb,
                                                   float* __restrict__ Fout,
                                                   int M, int write_f32, int doC) {
  // phase A: buf b @ b*28672: A[4KB] @0, B[24KB] @4096 (64B rows, chunk^=(r>>1)&3)
  // phase B: lin @0 (32KB), y @32768 (16KB, 256B rows); phase C: Wq @0, h @32768
  __shared__ __align__(16) unsigned char lds[57344];
  int tid = threadIdx.x;
  int w = tid >> 6, lane = tid & 63;   // w == wc (4 waves)
  int l16 = lane & 15, lhi = lane >> 4;
  int row0 = blockIdx.x * 64;
  const char* Xb = (const char*)X;
  int ra = tid >> 2;                   // 0..63
  int posa = (((tid & 3) ^ ((ra >> 1) & 3)) << 4);
  const char* srcA = Xb + (size_t)(row0 + ra) * 1280 + posa;
  unsigned dstA = tid * 16;            // 4KB
  const unsigned char* srcB = Bimg + tid * 16;
  unsigned dstB = 4096 + tid * 16;

  f32x4 acc[4][6];
#pragma unroll
  for (int m = 0; m < 4; m++)
#pragma unroll
    for (int f = 0; f < 6; f++) acc[m][f] = (f32x4){0.f, 0.f, 0.f, 0.f};

#define STAGE_AB(buf, kt)                                                          \
  do {                                                                             \
    unsigned base = (buf) * 28672u;                                                \
    gload16(srcA + (kt) * 64, lds + base + dstA);                                  \
    _Pragma("unroll") for (int j = 0; j < 6; j++)                                  \
        gload16(srcB + (size_t)(kt) * 24576 + j * 4096, lds + base + dstB + j * 4096); \
  } while (0)

#define COMPUTE_A(buf)                                                             \
  do {                                                                             \
    const unsigned char* LA = lds + (buf) * 28672u;                                \
    const unsigned char* LB = LA + 4096;                                           \
    int pb = lhi * 16;                                                             \
    bf16x8 af[4], bfr[6];                                                          \
    _Pragma("unroll") for (int m = 0; m < 4; m++)                                  \
        af[m] = rf64(LA, m * 16 + l16, pb);                                        \
    _Pragma("unroll") for (int f = 0; f < 6; f++)                                  \
        bfr[f] = rf64(LB, (f >> 1) * 128 + w * 32 + (f & 1) * 16 + l16, pb);       \
    _Pragma("unroll") for (int m = 0; m < 4; m++)                                  \
        _Pragma("unroll") for (int f = 0; f < 6; f++)                              \
            acc[m][f] =                                                            \
                __builtin_amdgcn_mfma_f32_16x16x32_bf16(af[m], bfr[f], acc[m][f], 0, 0, 0); \
  } while (0)

  // 2-deep counted-vmcnt pipeline over 20 K-tiles (7 loads/thread/stage)
  STAGE_AB(0, 0);
  STAGE_AB(1, 1);
  for (int kt = 0; kt < 20; kt++) {
    if (kt < 19) {
      asm volatile("s_waitcnt vmcnt(7)" ::: "memory");  // tile kt landed; kt+1 in flight
    } else {
      asm volatile("s_waitcnt vmcnt(0)" ::: "memory");
    }
    __builtin_amdgcn_s_barrier();
    __builtin_amdgcn_sched_barrier(0);
    __builtin_amdgcn_s_setprio(1);
    COMPUTE_A(kt & 1);
    __builtin_amdgcn_s_setprio(0);
    __builtin_amdgcn_sched_barrier(0);
    __builtin_amdgcn_s_barrier();  // all waves done reading buf[kt&1]
    if (kt < 18) STAGE_AB(kt & 1, kt + 2);
  }

  // stage lin image into @0 (8 loads/thread); combine epilogue hides the load
#pragma unroll
  for (int j = 0; j < 8; j++) {
    int off = w * 8192 + j * 1024;
    gload16(Limg + off + lane * 16, lds + off);
  }
  // combine epilogue -> y into LDS @32768 (64 rows x 256B swizzled)
#pragma unroll
  for (int m = 0; m < 4; m++)
#pragma unroll
    for (int i = 0; i < 4; i++) {
      int rl = m * 16 + lhi * 4 + i;
      int r = row0 + rl;
      float s = scale[r], iv = invs[r];
      int swz = (rl & 7) << 4;
#pragma unroll
      for (int j = 0; j < 2; j++) {
        int c = w * 32 + j * 16 + l16;
        float v = acc[m][j][i] + s * acc[m][2 + j][i] + iv * acc[m][4 + j][i] + biasg[c] +
                  s * biasg[128 + c] + iv * biasg[256 + c];
        *(unsigned short*)(lds + 32768 + rl * 256 + ((2 * c) ^ swz)) = f2bf(v);
      }
    }
  __syncthreads();  // drains lin stage + makes y visible

  // phase B: h = relu(y @ lin^T + lin_b)
  f32x4 acc2[4][2];
#pragma unroll
  for (int m = 0; m < 4; m++)
#pragma unroll
    for (int j = 0; j < 2; j++) acc2[m][j] = (f32x4){0.f, 0.f, 0.f, 0.f};
#pragma unroll
  for (int ks = 0; ks < 4; ks++) {
    int pb = ks * 64 + lhi * 16;
    bf16x8 af[4], bfr[2];
#pragma unroll
    for (int m = 0; m < 4; m++) af[m] = rf256(lds + 32768, m * 16 + l16, pb);
#pragma unroll
    for (int j = 0; j < 2; j++) bfr[j] = rf256(lds, w * 32 + j * 16 + l16, pb);
#pragma unroll
    for (int m = 0; m < 4; m++)
#pragma unroll
      for (int j = 0; j < 2; j++)
        acc2[m][j] = __builtin_amdgcn_mfma_f32_16x16x32_bf16(af[m], bfr[j], acc2[m][j], 0, 0, 0);
  }
  __syncthreads();  // all y/lin reads complete before overwrite

  // stage Wq @0; h epilogue: write Xh global (+Fout) and h into LDS @32768
  if (doC) {
#pragma unroll
    for (int j = 0; j < 8; j++) {
      int off = w * 8192 + j * 1024;
      gload16(Qimg + off + lane * 16, lds + off);
    }
  }
#pragma unroll
  for (int m = 0; m < 4; m++)
#pragma unroll
    for (int j = 0; j < 2; j++)
#pragma unroll
      for (int i = 0; i < 4; i++) {
        int rl = m * 16 + lhi * 4 + i;
        int r = row0 + rl;
        int c = w * 32 + j * 16 + l16;
        float v = fmaxf(acc2[m][j][i] + lin_b[c], 0.0f);
        unsigned short hb = f2bf(v);
        Xh[(size_t)r * 640 + c] = hb;
        if (doC) *(unsigned short*)(lds + 32768 + rl * 256 + ((2 * c) ^ ((rl & 7) << 4))) = hb;
        if (write_f32 && r < M) Fout[(size_t)r * 128 + c] = v;
      }
  if (!doC) return;
  __syncthreads();  // h visible + Wq staged (vmcnt drained)

  // phase C: Qb_next = h @ Wq^T
  f32x4 acc3[4][2];
#pragma unroll
  for (int m = 0; m < 4; m++)
#pragma unroll
    for (int j = 0; j < 2; j++) acc3[m][j] = (f32x4){0.f, 0.f, 0.f, 0.f};
#pragma unroll
  for (int ks = 0; ks < 4; ks++) {
    int pb = ks * 64 + lhi * 16;
    bf16x8 af[4], bfr[2];
#pragma unroll
    for (int m = 0; m < 4; m++) af[m] = rf256(lds + 32768, m * 16 + l16, pb);
#pragma unroll
    for (int j = 0; j < 2; j++) bfr[j] = rf256(lds, w * 32 + j * 16 + l16, pb);
#pragma unroll
    for (int m = 0; m < 4; m++)
#pragma unroll
      for (int j = 0; j < 2; j++)
        acc3[m][j] = __builtin_amdgcn_mfma_f32_16x16x32_bf16(af[m], bfr[j], acc3[m][j], 0, 0, 0);
  }
#pragma unroll
  for (int m = 0; m < 4; m++)
#pragma unroll
    for (int j = 0; j < 2; j++)
#pragma unroll
      for (int i = 0; i < 4; i++) {
        int r = row0 + m * 16 + lhi * 4 + i;
        int c = w * 32 + j * 16 + l16;
        Qb[(size_t)r * 128 + c] = f2bf(acc3[m][j][i]);
      }
#undef STAGE_AB
#undef COMPUTE_A
}

// ---------------- host ----------------
extern "C" void kernel_launch(void* const* d_in, const int* in_sizes, int n_in,
                              void* d_out, int out_size, void* d_ws, size_t ws_size,
                              hipStream_t stream) {
  const float* x = (const float*)d_in[0];
  const int* eidx = (const int*)d_in[1];
  int n = in_sizes[0] / 128;
  int E = in_sizes[1] / 2;
  int n_pad = (n + 127) & ~127;
  const int* src = eidx;
  const int* dst = eidx + E;

  Ptr5 pre_w, pre_b, adl, post_w, post_b, lin_w, lin_b;
  for (int i = 0; i < 5; i++) {
    pre_w.p[i] = (const float*)d_in[2 + i * 7 + 0];
    pre_b.p[i] = (const float*)d_in[2 + i * 7 + 1];
    adl.p[i] = (const float*)d_in[2 + i * 7 + 2];
    post_w.p[i] = (const float*)d_in[2 + i * 7 + 3];
    post_b.p[i] = (const float*)d_in[2 + i * 7 + 4];
    lin_w.p[i] = (const float*)d_in[2 + i * 7 + 5];
    lin_b.p[i] = (const float*)d_in[2 + i * 7 + 6];
  }

  char* ws = (char*)d_ws;
  size_t off = 0;
  auto alloc = [&](size_t bytes) {
    char* p = ws + off;
    off += (bytes + 255) & ~(size_t)255;
    return p;
  };
  unsigned short* X = (unsigned short*)alloc((size_t)n_pad * 640 * 2);  // [h | agg]
  unsigned short* Qb = (unsigned short*)alloc((size_t)n_pad * 128 * 2);
  float* scale = (float*)alloc((size_t)n_pad * 4);
  float* invs = (float*)alloc((size_t)n_pad * 4);
  int* deg = (int*)alloc((size_t)n * 4);
  int* row_start = (int*)alloc((size_t)(n + 1) * 4);
  int* cursor = (int*)alloc((size_t)n * 4);
  int* edge_src = (int*)alloc((size_t)E * 4);
  int nb = (n + 1023) / 1024;
  int* bsum = (int*)alloc((size_t)nb * 4);
  int* boff = (int*)alloc((size_t)nb * 4);
  float* Whg_base = (float*)alloc((size_t)5 * 3 * 128 * 128 * 4);
  UPtr5 Bpost, Lin, Qimg;
  FPtr5 biasg;
  for (int i = 0; i < 5; i++) {
    Bpost.p[i] = (unsigned char*)alloc(491520);
    Lin.p[i] = (unsigned char*)alloc(32768);
    Qimg.p[i] = (unsigned char*)alloc(32768);
    biasg.p[i] = (float*)alloc(384 * 4);
  }

  hipMemsetAsync(deg, 0, (size_t)n * 4, stream);
  k_hist<<<(E + 255) / 256, 256, 0, stream>>>(dst, deg, E);
  k_scan_part<<<nb, 256, 0, stream>>>(deg, bsum, n);
  k_scan_bsum<<<1, 64, 0, stream>>>(bsum, boff, row_start, nb, n);
  k_scan_final<<<nb, 256, 0, stream>>>(deg, boff, row_start, cursor, n);
  k_scatter<<<(E + 255) / 256, 256, 0, stream>>>(src, dst, cursor, edge_src, E);
  k_cast<<<(n * 32 + 255) / 256, 256, 0, stream>>>(x, X, n);
  k_fold5<<<dim3(192, 5), 256, 0, stream>>>(post_w, pre_w, pre_b, post_b, Whg_base, biasg);
  k_repack_post5<<<dim3(960, 5), 256, 0, stream>>>(post_w, Whg_base, Bpost);
  k_repack_ql5<<<dim3(64, 5, 2), 256, 0, stream>>>(pre_w, lin_w, Qimg, Lin);

  int g1blocks = n_pad / 128;
  int gblocks = n_pad / 64;
  k_gemm1<<<g1blocks, 512, 0, stream>>>(X, Qimg.p[0], Qb);
  for (int L = 0; L < 5; L++) {
    k_agg<<<(n + 7) / 8, 256, 0, stream>>>(Qb, row_start, edge_src, X, pre_w.p[L], pre_b.p[L],
                                           adl.p[L], X, scale, invs, n);
    k_fused<<<gblocks, 256, 0, stream>>>(X, Bpost.p[L], Lin.p[L],
                                         (L < 4) ? Qimg.p[L + 1] : Qimg.p[0], scale, invs,
                                         biasg.p[L], lin_b.p[L], X, Qb, (float*)d_out, n,
                                         (L == 4) ? 1 : 0, (L < 4) ? 1 : 0);
  }
}

// Round 21
// 488.290 us; speedup vs baseline: 1.3635x; 1.0272x over previous
//
#include <hip/hip_runtime.h>

typedef short bf16x8 __attribute__((ext_vector_type(8)));
typedef float f32x4 __attribute__((ext_vector_type(4)));

struct Ptr5 { const float* p[5]; };
struct UPtr5 { unsigned char* p[5]; };
struct FPtr5 { float* p[5]; };

__device__ __forceinline__ unsigned short f2bf(float f) {
  unsigned u = __float_as_uint(f);
  u += 0x7fffu + ((u >> 16) & 1u);
  return (unsigned short)(u >> 16);
}

__device__ __forceinline__ float bf2f(unsigned short h) {
  return __uint_as_float(((unsigned)h) << 16);
}

__device__ __forceinline__ void gload16(const void* g, void* l) {
  __builtin_amdgcn_global_load_lds((const __attribute__((address_space(1))) void*)g,
                                   (__attribute__((address_space(3))) void*)l, 16, 0, 0);
}

// 64B-row swizzled fragment read: chunk ^= (row>>1)&3 -> 2-way max (free)
__device__ __forceinline__ bf16x8 rf64(const unsigned char* lds, int row, int pb) {
  return *(const bf16x8*)(lds + row * 64 + (pb ^ ((((row) >> 1) & 3) << 4)));
}
// 256B-row swizzled fragment read (128 bf16 per row)
__device__ __forceinline__ bf16x8 rf256(const unsigned char* lds, int row, int pb) {
  return *(const bf16x8*)(lds + row * 256 + (pb ^ ((row & 7) << 4)));
}

// ---------------- CSR build ----------------
__global__ void k_hist(const int* __restrict__ dst, int* __restrict__ deg, int E) {
  int e = blockIdx.x * blockDim.x + threadIdx.x;
  if (e < E) atomicAdd(&deg[dst[e]], 1);
}

__global__ __launch_bounds__(256) void k_scan_part(const int* __restrict__ deg,
                                                    int* __restrict__ bsum, int n) {
  int b = blockIdx.x, t = threadIdx.x;
  int base = b * 1024 + t * 4;
  int s = 0;
#pragma unroll
  for (int i = 0; i < 4; i++) {
    int idx = base + i;
    if (idx < n) s += deg[idx];
  }
  for (int off = 1; off < 64; off <<= 1) s += __shfl_xor(s, off);
  __shared__ int ws[4];
  if ((t & 63) == 0) ws[t >> 6] = s;
  __syncthreads();
  if (t == 0) bsum[b] = ws[0] + ws[1] + ws[2] + ws[3];
}

__global__ void k_scan_bsum(const int* __restrict__ bsum, int* __restrict__ boff,
                            int* __restrict__ row_start, int nb, int n) {
  int t = threadIdx.x;
  int orig = (t < nb) ? bsum[t] : 0;
  int v = orig;
  for (int off = 1; off < 64; off <<= 1) {
    int u = __shfl_up(v, off);
    if (t >= off) v += u;
  }
  if (t < nb) boff[t] = v - orig;
  if (t == nb - 1) row_start[n] = v;
}

__global__ __launch_bounds__(256) void k_scan_final(const int* __restrict__ deg,
                                                     const int* __restrict__ boff,
                                                     int* __restrict__ row_start,
                                                     int* __restrict__ cursor, int n) {
  int b = blockIdx.x, t = threadIdx.x;
  int lane = t & 63, wid = t >> 6;
  int base = b * 1024 + t * 4;
  int v[4];
  int s = 0;
#pragma unroll
  for (int i = 0; i < 4; i++) {
    int idx = base + i;
    v[i] = (idx < n) ? deg[idx] : 0;
    s += v[i];
  }
  int sc = s;
  for (int off = 1; off < 64; off <<= 1) {
    int u = __shfl_up(sc, off);
    if (lane >= off) sc += u;
  }
  __shared__ int ws[4];
  if (lane == 63) ws[wid] = sc;
  __syncthreads();
  int wbase = 0;
  for (int i = 0; i < wid; i++) wbase += ws[i];
  int run = boff[b] + wbase + sc - s;
#pragma unroll
  for (int i = 0; i < 4; i++) {
    int idx = base + i;
    if (idx < n) {
      row_start[idx] = run;
      cursor[idx] = run;
      run += v[i];
    }
  }
}

__global__ void k_scatter(const int* __restrict__ src, const int* __restrict__ dst,
                          int* __restrict__ cursor, int* __restrict__ edge_src, int E) {
  int e = blockIdx.x * blockDim.x + threadIdx.x;
  if (e < E) {
    int pos = atomicAdd(&cursor[dst[e]], 1);
    edge_src[pos] = src[e];
  }
}

// ---------------- cast x -> X.h (row stride 640) ----------------
__global__ void k_cast(const float* __restrict__ x, unsigned short* __restrict__ X, int n) {
  int i = blockIdx.x * blockDim.x + threadIdx.x;
  if (i >= n * 32) return;
  int r = i >> 5, c = (i & 31) * 4;
  float4 v = *(const float4*)(x + (size_t)r * 128 + c);
  ushort4 o;
  o.x = f2bf(v.x); o.y = f2bf(v.y); o.z = f2bf(v.z); o.w = f2bf(v.w);
  *(ushort4*)(X + (size_t)r * 640 + c) = o;
}

// ---------------- fold, all 5 layers (blockIdx.y = layer) ----------------
__global__ __launch_bounds__(256) void k_fold5(Ptr5 post_w, Ptr5 pre_w, Ptr5 pre_b,
                                                Ptr5 post_b, float* __restrict__ Whg_base,
                                                FPtr5 biasg) {
  int L = blockIdx.y;
  int id = blockIdx.x * blockDim.x + threadIdx.x;
  if (id >= 3 * 128 * 128) return;
  int g = id >> 14;
  int rem = id & 16383;
  int j = rem >> 7, k = rem & 127;
  const float* pw = post_w.p[L] + j * 1664 + g * 512 + 128;
  const float* prw = pre_w.p[L];
  float acc = 0.f, bacc = 0.f;
  for (int f = 0; f < 128; f++) {
    float wc = pw[f] + pw[128 + f] + pw[256 + f];
    acc += wc * prw[f * 256 + k];
    if (k == 0) bacc += wc * pre_b.p[L][f];
  }
  Whg_base[L * 49152 + id] = acc;
  if (k == 0) biasg.p[L][g * 128 + j] = bacc + ((g == 0) ? post_b.p[L][j] : 0.f);
}

// ---------------- repack post (20 K-tiles x 384 rows x 64B, chunk^=(r>>1)&3), all 5 layers ----------------
__global__ void k_repack_post5(Ptr5 post_w, const float* __restrict__ Whg_base, UPtr5 img) {
  int L = blockIdx.y;
  int i = blockIdx.x * blockDim.x + threadIdx.x;
  if (i >= 384 * 640) return;
  const float* pwL = post_w.p[L];
  const float* Whg = Whg_base + L * 49152;
  unsigned char* im = img.p[L];
  int r = i / 640, k = i - r * 640;
  int g = r >> 7, jj = r & 127;
  float v;
  if (k < 128) v = ((g == 0) ? pwL[jj * 1664 + k] : 0.0f) + Whg[(g * 128 + jj) * 128 + k];
  else v = pwL[jj * 1664 + g * 512 + 128 + (k - 128)];
  int kt = k >> 5, kl = k & 31;
  int ch = kl >> 3, e = kl & 7;
  int off = kt * 24576 + r * 64 + ((ch ^ ((r >> 1) & 3)) << 4) + e * 2;
  *(unsigned short*)(im + off) = f2bf(v);
}

// ---------------- repack q (z=0) / lin (z=1), all 5 layers ----------------
__global__ void k_repack_ql5(Ptr5 pre_w, Ptr5 lin_w, UPtr5 qimg, UPtr5 limg) {
  int L = blockIdx.y;
  int which = blockIdx.z;
  int i = blockIdx.x * blockDim.x + threadIdx.x;
  if (i >= 128 * 128) return;
  int j = i >> 7, k = i & 127;
  float v = which ? lin_w.p[L][i] : pre_w.p[L][j * 256 + 128 + k];
  unsigned char* im = which ? limg.p[L] : qimg.p[L];
  int ch = k >> 3, e = k & 7;
  int off = j * 256 + ((ch * 16) ^ ((j & 7) << 4)) + e * 2;
  *(unsigned short*)(im + off) = f2bf(v);
}

// ---------------- GEMM1 (layer 0 only): Qb = X.h @ Wq^T ----------------
__global__ __launch_bounds__(512, 2) void k_gemm1(const unsigned short* __restrict__ X,
                                                   const unsigned char* __restrict__ Qimg,
                                                   unsigned short* __restrict__ Qb) {
  __shared__ __align__(16) unsigned char lds[65536];
  int tid = threadIdx.x;
  int w = tid >> 6, lane = tid & 63;
  int wr = w >> 2, wc = w & 3;
  int l16 = lane & 15, lhi = lane >> 4;
  int row0 = blockIdx.x * 128;
  const char* Xb = (const char*)X;
#pragma unroll
  for (int j = 0; j < 4; j++) {
    int off = w * 4096 + j * 1024 + lane * 16;
    int r = off >> 8, pos = off & 255;
    int ch = (pos ^ ((r & 7) << 4)) >> 4;
    gload16(Xb + (size_t)(row0 + r) * 1280 + ch * 16, lds + w * 4096 + j * 1024);
  }
#pragma unroll
  for (int j = 0; j < 4; j++) {
    int off = w * 4096 + j * 1024;
    gload16(Qimg + off + lane * 16, lds + 32768 + off);
  }
  __syncthreads();
  f32x4 acc[4][2];
#pragma unroll
  for (int m = 0; m < 4; m++)
#pragma unroll
    for (int j = 0; j < 2; j++) acc[m][j] = (f32x4){0.f, 0.f, 0.f, 0.f};
#pragma unroll
  for (int ks = 0; ks < 4; ks++) {
    int pb = ks * 64 + lhi * 16;
    bf16x8 af[4], bfr[2];
#pragma unroll
    for (int m = 0; m < 4; m++) af[m] = rf256(lds, wr * 64 + m * 16 + l16, pb);
#pragma unroll
    for (int j = 0; j < 2; j++) bfr[j] = rf256(lds + 32768, wc * 32 + j * 16 + l16, pb);
#pragma unroll
    for (int m = 0; m < 4; m++)
#pragma unroll
      for (int j = 0; j < 2; j++)
        acc[m][j] = __builtin_amdgcn_mfma_f32_16x16x32_bf16(af[m], bfr[j], acc[m][j], 0, 0, 0);
  }
#pragma unroll
  for (int m = 0; m < 4; m++)
#pragma unroll
    for (int j = 0; j < 2; j++)
#pragma unroll
      for (int i = 0; i < 4; i++) {
        int r = row0 + wr * 64 + m * 16 + lhi * 4 + i;
        int c = wc * 32 + j * 16 + l16;
        Qb[(size_t)r * 128 + c] = f2bf(acc[m][j][i]);
      }
}

// ---------------- aggregation: 2 independent nodes per wave (half-wave per node) ----------------
__global__ __launch_bounds__(256) void k_agg(const unsigned short* __restrict__ Qb,
                                              const int* __restrict__ row_start,
                                              const int* __restrict__ edge_src,
                                              const unsigned short* __restrict__ X_h,
                                              const float* __restrict__ pre_w,
                                              const float* __restrict__ pre_b,
                                              const float* __restrict__ adl,
                                              unsigned short* __restrict__ X,
                                              float* __restrict__ scale,
                                              float* __restrict__ inv_scale, int n) {
  int wv = (blockIdx.x * blockDim.x + threadIdx.x) >> 6;
  int lane = threadIdx.x & 63;
  int half = lane >> 5, fl = lane & 31;  // half-wave owns node v; lane covers features 4fl..4fl+3
  int v = 2 * wv + half;
  if (v >= n) return;
  int r0 = row_start[v], r1 = row_start[v + 1];
  int dg = r1 - r0;
  float mean[4], mnv[4], mxv[4], sdv[4];
  if (dg > 0) {
    float s[4] = {0.f, 0.f, 0.f, 0.f}, q[4] = {0.f, 0.f, 0.f, 0.f};
    float mn[4], mx[4];
#pragma unroll
    for (int t = 0; t < 4; t++) { mn[t] = INFINITY; mx[t] = -INFINITY; }
    const unsigned char* qbase = (const unsigned char*)Qb;
#define ACC4(U)                                                              \
  do {                                                                       \
    float f0 = __uint_as_float((U).x << 16);                                 \
    float f1 = __uint_as_float((U).x & 0xffff0000u);                         \
    float f2 = __uint_as_float((U).y << 16);                                 \
    float f3 = __uint_as_float((U).y & 0xffff0000u);                         \
    s[0] += f0; s[1] += f1; s[2] += f2; s[3] += f3;                          \
    q[0] += f0 * f0; q[1] += f1 * f1; q[2] += f2 * f2; q[3] += f3 * f3;      \
    mn[0] = fminf(mn[0], f0); mn[1] = fminf(mn[1], f1);                      \
    mn[2] = fminf(mn[2], f2); mn[3] = fminf(mn[3], f3);                      \
    mx[0] = fmaxf(mx[0], f0); mx[1] = fmaxf(mx[1], f1);                      \
    mx[2] = fmaxf(mx[2], f2); mx[3] = fmaxf(mx[3], f3);                      \
  } while (0)
    int e = r0;
    for (; e + 3 < r1; e += 4) {  // 4 rows in flight per half-wave
      int sa = edge_src[e], sb = edge_src[e + 1], sc = edge_src[e + 2], sd = edge_src[e + 3];
      uint2 ua = *(const uint2*)(qbase + (size_t)sa * 256 + 8 * fl);
      uint2 ub = *(const uint2*)(qbase + (size_t)sb * 256 + 8 * fl);
      uint2 uc = *(const uint2*)(qbase + (size_t)sc * 256 + 8 * fl);
      uint2 ud = *(const uint2*)(qbase + (size_t)sd * 256 + 8 * fl);
      ACC4(ua); ACC4(ub); ACC4(uc); ACC4(ud);
    }
    for (; e < r1; e++) {
      int sa = edge_src[e];
      uint2 ua = *(const uint2*)(qbase + (size_t)sa * 256 + 8 * fl);
      ACC4(ua);
    }
#undef ACC4
    float invd = 1.0f / (float)dg;
#pragma unroll
    for (int t = 0; t < 4; t++) {
      mean[t] = s[t] * invd;
      float var = fmaxf(q[t] * invd - mean[t] * mean[t], 0.f);
      sdv[t] = sqrtf(var + 1e-5f);
      mnv[t] = mn[t]; mxv[t] = mx[t];
    }
  } else {
    // rare: cancel folded c-term by storing -c
    const unsigned short* hv = X_h + (size_t)v * 640;
#pragma unroll
    for (int t = 0; t < 4; t++) {
      int j = 4 * fl + t;
      float c = pre_b[j];
      for (int k = 0; k < 128; k++) c += bf2f(hv[k]) * pre_w[j * 256 + k];
      mean[t] = mnv[t] = mxv[t] = -c;
      sdv[t] = sqrtf(1e-5f);
    }
  }
  unsigned short* row = X + (size_t)v * 640 + 128;
  ushort4 wm, wn, wx, ws;
  wm.x = f2bf(mean[0]); wm.y = f2bf(mean[1]); wm.z = f2bf(mean[2]); wm.w = f2bf(mean[3]);
  wn.x = f2bf(mnv[0]);  wn.y = f2bf(mnv[1]);  wn.z = f2bf(mnv[2]);  wn.w = f2bf(mnv[3]);
  wx.x = f2bf(mxv[0]);  wx.y = f2bf(mxv[1]);  wx.z = f2bf(mxv[2]);  wx.w = f2bf(mxv[3]);
  ws.x = f2bf(sdv[0]);  ws.y = f2bf(sdv[1]);  ws.z = f2bf(sdv[2]);  ws.w = f2bf(sdv[3]);
  *(ushort4*)(row + 4 * fl) = wm;
  *(ushort4*)(row + 128 + 4 * fl) = wn;
  *(ushort4*)(row + 256 + 4 * fl) = wx;
  *(ushort4*)(row + 384 + 4 * fl) = ws;
  if (fl == 0) {
    float degf = (float)dg;
    float sc = logf(fmaxf(degf, 1.0f) + 1.0f) / adl[0];
    scale[v] = sc;
    inv_scale[v] = 1.0f / sc;
  }
}

// ------- fused: post GEMM (K=640, BK=32, 3-buffer single-barrier pipeline) + combine + lin + next-Q -------
// 96KB buffers + phases -> 1 block/CU
__global__ __launch_bounds__(512, 2) void k_fused(const unsigned short* __restrict__ X,
                                                   const unsigned char* __restrict__ Bimg,
                                                   const unsigned char* __restrict__ Limg,
                                                   const unsigned char* __restrict__ Qimg,
                                                   const float* __restrict__ scale,
                                                   const float* __restrict__ invs,
                                                   const float* __restrict__ biasg,
                                                   const float* __restrict__ lin_b,
                                                   unsigned short* __restrict__ Xh,
                                                   unsigned short* __restrict__ Qb,
                                                   float* __restrict__ Fout,
                                                   int M, int write_f32, int doC) {
  // phase A: buf b @ b*32768 (b=0,1,2): A[8KB] @0, B[24KB] @8192 (64B rows, chunk^=(r>>1)&3)
  // phase B: lin @0 (32KB), y @32768 (32KB, 256B rows)
  // phase C: Wq @0, h @32768
  __shared__ __align__(16) unsigned char lds[98304];
  int tid = threadIdx.x;
  int w = tid >> 6, lane = tid & 63;
  int wr = w >> 2, wc = w & 3;
  int l16 = lane & 15, lhi = lane >> 4;
  int row0 = blockIdx.x * 128;
  const char* Xb = (const char*)X;
  int ra = tid >> 2;
  int posa = (((tid & 3) ^ ((ra >> 1) & 3)) << 4);
  const char* srcA = Xb + (size_t)(row0 + ra) * 1280 + posa;
  unsigned dstA = tid * 16;
  const unsigned char* srcB = Bimg + tid * 16;
  unsigned dstB = 8192 + tid * 16;

  f32x4 acc[4][6];
#pragma unroll
  for (int m = 0; m < 4; m++)
#pragma unroll
    for (int f = 0; f < 6; f++) acc[m][f] = (f32x4){0.f, 0.f, 0.f, 0.f};

#define STAGE_AB(buf, kt)                                                          \
  do {                                                                             \
    unsigned base = (buf) * 32768u;                                                \
    gload16(srcA + (kt) * 64, lds + base + dstA);                                  \
    _Pragma("unroll") for (int j = 0; j < 3; j++)                                  \
        gload16(srcB + (size_t)(kt) * 24576 + j * 8192, lds + base + dstB + j * 8192); \
  } while (0)

#define COMPUTE_A(buf)                                                             \
  do {                                                                             \
    const unsigned char* LA = lds + (buf) * 32768u;                                \
    const unsigned char* LB = LA + 8192;                                           \
    int pb = lhi * 16;                                                             \
    bf16x8 af[4], bfr[6];                                                          \
    _Pragma("unroll") for (int m = 0; m < 4; m++)                                  \
        af[m] = rf64(LA, wr * 64 + m * 16 + l16, pb);                              \
    _Pragma("unroll") for (int f = 0; f < 6; f++)                                  \
        bfr[f] = rf64(LB, (f >> 1) * 128 + wc * 32 + (f & 1) * 16 + l16, pb);      \
    _Pragma("unroll") for (int m = 0; m < 4; m++)                                  \
        _Pragma("unroll") for (int f = 0; f < 6; f++)                              \
            acc[m][f] =                                                            \
                __builtin_amdgcn_mfma_f32_16x16x32_bf16(af[m], bfr[f], acc[m][f], 0, 0, 0); \
  } while (0)

  // 3-buffer, single-barrier, 2-tile-lead pipeline over 20 K-tiles (4 wave-loads/stage)
  STAGE_AB(0, 0);
  STAGE_AB(1, 1);
  int buf = 0;
  for (int kt = 0; kt < 20; kt++) {
    if (kt < 19) {
      asm volatile("s_waitcnt vmcnt(4)" ::: "memory");  // tile kt landed; kt+1 in flight
    } else {
      asm volatile("s_waitcnt vmcnt(0)" ::: "memory");
    }
    __builtin_amdgcn_s_barrier();   // all waves have tile kt; all done computing kt-1
    __builtin_amdgcn_sched_barrier(0);
    if (kt < 18) {
      int nb3 = buf + 2;
      if (nb3 >= 3) nb3 -= 3;
      STAGE_AB(nb3, kt + 2);  // overwrites buffer of tile kt-1 (fenced by barrier above)
    }
    __builtin_amdgcn_s_setprio(1);
    COMPUTE_A(buf);
    __builtin_amdgcn_s_setprio(0);
    __builtin_amdgcn_sched_barrier(0);
    buf++;
    if (buf == 3) buf = 0;
  }
  __builtin_amdgcn_s_barrier();  // all compute(19) reads done before epilogue overwrites LDS

  // stage lin image into @0; combine epilogue hides the load
#pragma unroll
  for (int j = 0; j < 4; j++) {
    int off = w * 4096 + j * 1024;
    gload16(Limg + off + lane * 16, lds + off);
  }
  // combine epilogue -> y into LDS @32768 (256B swizzled rows)
#pragma unroll
  for (int m = 0; m < 4; m++)
#pragma unroll
    for (int i = 0; i < 4; i++) {
      int rl = wr * 64 + m * 16 + lhi * 4 + i;
      int r = row0 + rl;
      float s = scale[r], iv = invs[r];
      int swz = (rl & 7) << 4;
#pragma unroll
      for (int j = 0; j < 2; j++) {
        int c = wc * 32 + j * 16 + l16;
        float v = acc[m][j][i] + s * acc[m][2 + j][i] + iv * acc[m][4 + j][i] + biasg[c] +
                  s * biasg[128 + c] + iv * biasg[256 + c];
        *(unsigned short*)(lds + 32768 + rl * 256 + ((2 * c) ^ swz)) = f2bf(v);
      }
    }
  __syncthreads();  // drains lin stage + makes y visible

  // phase B: h = relu(y @ lin^T + lin_b)
  f32x4 acc2[4][2];
#pragma unroll
  for (int m = 0; m < 4; m++)
#pragma unroll
    for (int j = 0; j < 2; j++) acc2[m][j] = (f32x4){0.f, 0.f, 0.f, 0.f};
#pragma unroll
  for (int ks = 0; ks < 4; ks++) {
    int pb = ks * 64 + lhi * 16;
    bf16x8 af[4], bfr[2];
#pragma unroll
    for (int m = 0; m < 4; m++) af[m] = rf256(lds + 32768, wr * 64 + m * 16 + l16, pb);
#pragma unroll
    for (int j = 0; j < 2; j++) bfr[j] = rf256(lds, wc * 32 + j * 16 + l16, pb);
#pragma unroll
    for (int m = 0; m < 4; m++)
#pragma unroll
      for (int j = 0; j < 2; j++)
        acc2[m][j] = __builtin_amdgcn_mfma_f32_16x16x32_bf16(af[m], bfr[j], acc2[m][j], 0, 0, 0);
  }
  __syncthreads();  // all y/lin reads complete before overwrite

  // stage Wq @0; h epilogue: write Xh global (+Fout) and h into LDS @32768
  if (doC) {
#pragma unroll
    for (int j = 0; j < 4; j++) {
      int off = w * 4096 + j * 1024;
      gload16(Qimg + off + lane * 16, lds + off);
    }
  }
#pragma unroll
  for (int m = 0; m < 4; m++)
#pragma unroll
    for (int j = 0; j < 2; j++)
#pragma unroll
      for (int i = 0; i < 4; i++) {
        int rl = wr * 64 + m * 16 + lhi * 4 + i;
        int r = row0 + rl;
        int c = wc * 32 + j * 16 + l16;
        float v = fmaxf(acc2[m][j][i] + lin_b[c], 0.0f);
        unsigned short hb = f2bf(v);
        Xh[(size_t)r * 640 + c] = hb;
        if (doC) *(unsigned short*)(lds + 32768 + rl * 256 + ((2 * c) ^ ((rl & 7) << 4))) = hb;
        if (write_f32 && r < M) Fout[(size_t)r * 128 + c] = v;
      }
  if (!doC) return;
  __syncthreads();  // h visible + Wq staged (vmcnt drained)

  // phase C: Qb_next = h @ Wq^T
  f32x4 acc3[4][2];
#pragma unroll
  for (int m = 0; m < 4; m++)
#pragma unroll
    for (int j = 0; j < 2; j++) acc3[m][j] = (f32x4){0.f, 0.f, 0.f, 0.f};
#pragma unroll
  for (int ks = 0; ks < 4; ks++) {
    int pb = ks * 64 + lhi * 16;
    bf16x8 af[4], bfr[2];
#pragma unroll
    for (int m = 0; m < 4; m++) af[m] = rf256(lds + 32768, wr * 64 + m * 16 + l16, pb);
#pragma unroll
    for (int j = 0; j < 2; j++) bfr[j] = rf256(lds, wc * 32 + j * 16 + l16, pb);
#pragma unroll
    for (int m = 0; m < 4; m++)
#pragma unroll
      for (int j = 0; j < 2; j++)
        acc3[m][j] = __builtin_amdgcn_mfma_f32_16x16x32_bf16(af[m], bfr[j], acc3[m][j], 0, 0, 0);
  }
#pragma unroll
  for (int m = 0; m < 4; m++)
#pragma unroll
    for (int j = 0; j < 2; j++)
#pragma unroll
      for (int i = 0; i < 4; i++) {
        int r = row0 + wr * 64 + m * 16 + lhi * 4 + i;
        int c = wc * 32 + j * 16 + l16;
        Qb[(size_t)r * 128 + c] = f2bf(acc3[m][j][i]);
      }
#undef STAGE_AB
#undef COMPUTE_A
}

// ---------------- host ----------------
extern "C" void kernel_launch(void* const* d_in, const int* in_sizes, int n_in,
                              void* d_out, int out_size, void* d_ws, size_t ws_size,
                              hipStream_t stream) {
  const float* x = (const float*)d_in[0];
  const int* eidx = (const int*)d_in[1];
  int n = in_sizes[0] / 128;
  int E = in_sizes[1] / 2;
  int n_pad = (n + 127) & ~127;
  const int* src = eidx;
  const int* dst = eidx + E;

  Ptr5 pre_w, pre_b, adl, post_w, post_b, lin_w, lin_b;
  for (int i = 0; i < 5; i++) {
    pre_w.p[i] = (const float*)d_in[2 + i * 7 + 0];
    pre_b.p[i] = (const float*)d_in[2 + i * 7 + 1];
    adl.p[i] = (const float*)d_in[2 + i * 7 + 2];
    post_w.p[i] = (const float*)d_in[2 + i * 7 + 3];
    post_b.p[i] = (const float*)d_in[2 + i * 7 + 4];
    lin_w.p[i] = (const float*)d_in[2 + i * 7 + 5];
    lin_b.p[i] = (const float*)d_in[2 + i * 7 + 6];
  }

  char* ws = (char*)d_ws;
  size_t off = 0;
  auto alloc = [&](size_t bytes) {
    char* p = ws + off;
    off += (bytes + 255) & ~(size_t)255;
    return p;
  };
  unsigned short* X = (unsigned short*)alloc((size_t)n_pad * 640 * 2);  // [h | agg]
  unsigned short* Qb = (unsigned short*)alloc((size_t)n_pad * 128 * 2);
  float* scale = (float*)alloc((size_t)n_pad * 4);
  float* invs = (float*)alloc((size_t)n_pad * 4);
  int* deg = (int*)alloc((size_t)n * 4);
  int* row_start = (int*)alloc((size_t)(n + 1) * 4);
  int* cursor = (int*)alloc((size_t)n * 4);
  int* edge_src = (int*)alloc((size_t)E * 4);
  int nb = (n + 1023) / 1024;
  int* bsum = (int*)alloc((size_t)nb * 4);
  int* boff = (int*)alloc((size_t)nb * 4);
  float* Whg_base = (float*)alloc((size_t)5 * 3 * 128 * 128 * 4);
  UPtr5 Bpost, Lin, Qimg;
  FPtr5 biasg;
  for (int i = 0; i < 5; i++) {
    Bpost.p[i] = (unsigned char*)alloc(491520);
    Lin.p[i] = (unsigned char*)alloc(32768);
    Qimg.p[i] = (unsigned char*)alloc(32768);
    biasg.p[i] = (float*)alloc(384 * 4);
  }

  hipMemsetAsync(deg, 0, (size_t)n * 4, stream);
  k_hist<<<(E + 255) / 256, 256, 0, stream>>>(dst, deg, E);
  k_scan_part<<<nb, 256, 0, stream>>>(deg, bsum, n);
  k_scan_bsum<<<1, 64, 0, stream>>>(bsum, boff, row_start, nb, n);
  k_scan_final<<<nb, 256, 0, stream>>>(deg, boff, row_start, cursor, n);
  k_scatter<<<(E + 255) / 256, 256, 0, stream>>>(src, dst, cursor, edge_src, E);
  k_cast<<<(n * 32 + 255) / 256, 256, 0, stream>>>(x, X, n);
  k_fold5<<<dim3(192, 5), 256, 0, stream>>>(post_w, pre_w, pre_b, post_b, Whg_base, biasg);
  k_repack_post5<<<dim3(960, 5), 256, 0, stream>>>(post_w, Whg_base, Bpost);
  k_repack_ql5<<<dim3(64, 5, 2), 256, 0, stream>>>(pre_w, lin_w, Qimg, Lin);

  int gblocks = n_pad / 128;
  k_gemm1<<<gblocks, 512, 0, stream>>>(X, Qimg.p[0], Qb);
  for (int L = 0; L < 5; L++) {
    k_agg<<<(n + 7) / 8, 256, 0, stream>>>(Qb, row_start, edge_src, X, pre_w.p[L], pre_b.p[L],
                                           adl.p[L], X, scale, invs, n);
    k_fused<<<gblocks, 512, 0, stream>>>(X, Bpost.p[L], Lin.p[L],
                                         (L < 4) ? Qimg.p[L + 1] : Qimg.p[0], scale, invs,
                                         biasg.p[L], lin_b.p[L], X, Qb, (float*)d_out, n,
                                         (L == 4) ? 1 : 0, (L < 4) ? 1 : 0);
  }
}